// Round 11
// baseline (206.136 us; speedup 1.0000x reference)
//
#include <hip/hip_runtime.h>

#define NN 50000
#define NE 800000
#define DD 96
#define HH 32
#define OO 4
#define ELLW 64             // max degree; deg ~ Poisson(16), guarded/clamped
#define NBUCK 391           // 128-node buckets: (50000+127)/128
#define BCAP 4096           // per-bucket edge capacity (mean ~2046, sd ~45)

typedef unsigned short ushort_t;
typedef unsigned int uint_t;
typedef __attribute__((ext_vector_type(8))) short short8;
typedef __attribute__((ext_vector_type(4))) float f32x4;

__device__ inline ushort_t f2bf(float f) {
    uint_t b = __float_as_uint(f);
    return (ushort_t)((b + 0x7fffu + ((b >> 16) & 1u)) >> 16);   // RNE
}

__device__ inline void addbf8(float* a, uint4 u) {
    a[0] += __uint_as_float(u.x << 16);
    a[1] += __uint_as_float(u.x & 0xffff0000u);
    a[2] += __uint_as_float(u.y << 16);
    a[3] += __uint_as_float(u.y & 0xffff0000u);
    a[4] += __uint_as_float(u.z << 16);
    a[5] += __uint_as_float(u.z & 0xffff0000u);
    a[6] += __uint_as_float(u.w << 16);
    a[7] += __uint_as_float(u.w & 0xffff0000u);
}

// ================= k1: edge bucketing (A) | W1b/W2a frag swizzle | y1 = x @ W1a ============

#define BA_B   ((NE / 4 + 255) / 256)        // 782
#define WF_B   6                              // 1152 (W1b) + 384 (W2a) frag-threads
#define MT1    (NN / 16)                      // 3125 M tiles
#define MFMA1_B ((MT1 + 3) / 4)               // 782

__global__ void k_big1(const int* __restrict__ edges, int* __restrict__ bcnt,
                       uint_t* __restrict__ packed,
                       const float* __restrict__ W1b, const float* __restrict__ W2a,
                       ushort_t* __restrict__ wf,
                       const float* __restrict__ x, const float* __restrict__ W1a,
                       ushort_t* __restrict__ y1) {
    int b = blockIdx.x;
    if (b < BA_B) {
        __shared__ int hist[NBUCK];
        __shared__ int basesh[NBUCK];
        int thr = threadIdx.x;
        int t4 = b * 256 + thr;
        bool live = t4 < NE / 4;
        int4 ss = {0,0,0,0}, tt = {0,0,0,0};
        if (live) {
            ss = ((const int4*)edges)[t4];
            tt = ((const int4*)(edges + NE))[t4];
        }
        for (int t = thr; t < NBUCK; t += 256) hist[t] = 0;
        __syncthreads();
        if (live) {
            atomicAdd(&hist[tt.x >> 7], 1);
            atomicAdd(&hist[tt.y >> 7], 1);
            atomicAdd(&hist[tt.z >> 7], 1);
            atomicAdd(&hist[tt.w >> 7], 1);
        }
        __syncthreads();
        for (int t = thr; t < NBUCK; t += 256) {
            int c = hist[t];
            basesh[t] = c ? atomicAdd(&bcnt[t], c) : 0;
        }
        __syncthreads();
        for (int t = thr; t < NBUCK; t += 256) hist[t] = 0;
        __syncthreads();
        if (live) {
            int d0 = tt.x, d1 = tt.y, d2 = tt.z, d3 = tt.w;
            int b0 = d0 >> 7, b1 = d1 >> 7, b2 = d2 >> 7, b3 = d3 >> 7;
            int p0 = basesh[b0] + atomicAdd(&hist[b0], 1);
            int p1 = basesh[b1] + atomicAdd(&hist[b1], 1);
            int p2 = basesh[b2] + atomicAdd(&hist[b2], 1);
            int p3 = basesh[b3] + atomicAdd(&hist[b3], 1);
            if (p0 < BCAP) packed[(size_t)b0 * BCAP + p0] = ((uint_t)ss.x << 7) | (d0 & 127);
            if (p1 < BCAP) packed[(size_t)b1 * BCAP + p1] = ((uint_t)ss.y << 7) | (d1 & 127);
            if (p2 < BCAP) packed[(size_t)b2 * BCAP + p2] = ((uint_t)ss.z << 7) | (d2 & 127);
            if (p3 < BCAP) packed[(size_t)b3 * BCAP + p3] = ((uint_t)ss.w << 7) | (d3 & 127);
        }
        return;
    }
    b -= BA_B;
    if (b < WF_B) {
        int tw = b * 256 + threadIdx.x;
        if (tw < 1152 + 384) {
            const float* Wsrc; ushort_t* dst; int KOUT, fl;
            if (tw < 1152) { Wsrc = W1b; dst = wf;        KOUT = DD; fl = tw; }
            else           { Wsrc = W2a; dst = wf + 9216; KOUT = HH; fl = tw - 1152; }
            int lane = fl & 63;
            int fc = fl >> 6;
            int c = fc % 3, nt = fc / 3;
            int kb = c * 32 + (lane >> 4) * 8;
            int col = nt * 16 + (lane & 15);
            ushort_t v[8];
#pragma unroll
            for (int j = 0; j < 8; ++j)
                v[j] = f2bf(Wsrc[(size_t)(kb + j) * KOUT + col]);
            *(uint4*)(dst + (size_t)fl * 8) = *(uint4*)v;
        }
        return;
    }
    b -= WF_B;
    constexpr int KC = 3, NT = 6;
    int lane = threadIdx.x & 63;
    int widx = threadIdx.x >> 6;
    int tile = b * 4 + widx;
    if (tile >= MT1) return;
    int row0 = tile * 16;
    int q = lane >> 4;
    int l16 = lane & 15;

    short8 bf[NT][KC];
#pragma unroll
    for (int nt = 0; nt < NT; ++nt)
#pragma unroll
        for (int c = 0; c < KC; ++c) {
            ushort_t v[8];
#pragma unroll
            for (int j = 0; j < 8; ++j)
                v[j] = f2bf(W1a[(size_t)(c * 32 + q * 8 + j) * DD + nt * 16 + l16]);
            bf[nt][c] = *(short8*)v;
        }

    short8 af[KC];
#pragma unroll
    for (int c = 0; c < KC; ++c) {
        const float* ap = x + (size_t)(row0 + l16) * DD + c * 32 + q * 8;
        float4 f0 = *(const float4*)ap;
        float4 f1 = *(const float4*)(ap + 4);
        ushort_t v[8] = {f2bf(f0.x), f2bf(f0.y), f2bf(f0.z), f2bf(f0.w),
                         f2bf(f1.x), f2bf(f1.y), f2bf(f1.z), f2bf(f1.w)};
        af[c] = *(short8*)v;
    }

    f32x4 acc[NT];
#pragma unroll
    for (int nt = 0; nt < NT; ++nt) acc[nt] = (f32x4){0.f, 0.f, 0.f, 0.f};
#pragma unroll
    for (int nt = 0; nt < NT; ++nt)
#pragma unroll
        for (int c = 0; c < KC; ++c)
            acc[nt] = __builtin_amdgcn_mfma_f32_16x16x32_bf16(af[c], bf[nt][c], acc[nt], 0, 0, 0);

#pragma unroll
    for (int nt = 0; nt < NT; ++nt) {
        int col = nt * 16 + l16;
#pragma unroll
        for (int r = 0; r < 4; ++r)
            y1[(size_t)(row0 + q * 4 + r) * DD + col] = f2bf(acc[nt][r]);
    }
}

// ================= phase B: per-bucket ELL fill via LDS counters (128-node buckets) =========

__global__ void k_bucketB(const int* __restrict__ bcnt, const uint_t* __restrict__ packed,
                          ushort_t* __restrict__ ell, int* __restrict__ deg) {
    __shared__ int curL[128];
    int b = blockIdx.x;
    int thr = threadIdx.x;
    int n0 = b * 128;
    if (thr < 128) curL[thr] = 0;
    __syncthreads();
    int cnt = min(bcnt[b], BCAP);
    const uint_t* pk = packed + (size_t)b * BCAP;
    for (int e = thr; e < cnt; e += 256) {
        uint_t u = pk[e];
        int doff = u & 127;
        int src = u >> 7;
        int p = atomicAdd(&curL[doff], 1);
        if (p < ELLW) ell[(size_t)(n0 + doff) * ELLW + p] = (ushort_t)src;
    }
    __syncthreads();
    if (thr < 128 && n0 + thr < NN) deg[n0 + thr] = curL[thr];
}

// ================= agg layer 1: 4-way edge split, 12 slices/row =============================
// thread layout: idx = i*48 + v*4 + part; parts in adjacent lanes (xor 1, 2).

__global__ void k_aggb96(const ushort_t* __restrict__ y, const int* __restrict__ deg,
                         const ushort_t* __restrict__ ell, const float* __restrict__ eps_p,
                         const float* __restrict__ b, ushort_t* __restrict__ out) {
    constexpr int V = DD / 8;   // 12 slices
    int idx = blockIdx.x * blockDim.x + threadIdx.x;
    if (idx >= NN * V * 4) return;
    int i = idx / (V * 4);
    int rem = idx - i * (V * 4);
    int v = rem >> 2, part = rem & 3;
    const uint4* y4 = (const uint4*)y;
    const ushort_t* er = ell + (size_t)i * ELLW;
    int d = min(deg[i], ELLW);
    float a0[8] = {0,0,0,0,0,0,0,0}, a1[8] = {0,0,0,0,0,0,0,0};
    float a2[8] = {0,0,0,0,0,0,0,0}, a3[8] = {0,0,0,0,0,0,0,0};
    int p = part;
    for (; p + 12 < d; p += 16) {
        int s0 = er[p], s1 = er[p+4], s2 = er[p+8], s3 = er[p+12];
        uint4 f0 = y4[(size_t)s0 * V + v];
        uint4 f1 = y4[(size_t)s1 * V + v];
        uint4 f2 = y4[(size_t)s2 * V + v];
        uint4 f3 = y4[(size_t)s3 * V + v];
        addbf8(a0, f0); addbf8(a1, f1); addbf8(a2, f2); addbf8(a3, f3);
    }
    for (; p < d; p += 4) addbf8(a0, y4[(size_t)er[p] * V + v]);

    float s[8];
#pragma unroll
    for (int k = 0; k < 8; ++k) {
        s[k] = (a0[k] + a1[k]) + (a2[k] + a3[k]);
        s[k] += __shfl_xor(s[k], 1);
        s[k] += __shfl_xor(s[k], 2);
    }
    if (part) return;

    uint4 su = y4[(size_t)i * V + v];
    float s8[8];
    s8[0] = __uint_as_float(su.x << 16); s8[1] = __uint_as_float(su.x & 0xffff0000u);
    s8[2] = __uint_as_float(su.y << 16); s8[3] = __uint_as_float(su.y & 0xffff0000u);
    s8[4] = __uint_as_float(su.z << 16); s8[5] = __uint_as_float(su.z & 0xffff0000u);
    s8[6] = __uint_as_float(su.w << 16); s8[7] = __uint_as_float(su.w & 0xffff0000u);
    float4 bl = ((const float4*)b)[2 * v];
    float4 bhv = ((const float4*)b)[2 * v + 1];
    float bb[8] = {bl.x, bl.y, bl.z, bl.w, bhv.x, bhv.y, bhv.z, bhv.w};
    float e = 1.0f + eps_p[0];
    ushort_t r[8];
#pragma unroll
    for (int k = 0; k < 8; ++k) {
        float vv = fmaf(e, s8[k], s[k]) + bb[k];
        r[k] = f2bf(fmaxf(vv, 0.0f));
    }
    uint4 o;
    o.x = (uint_t)r[0] | ((uint_t)r[1] << 16);
    o.y = (uint_t)r[2] | ((uint_t)r[3] << 16);
    o.z = (uint_t)r[4] | ((uint_t)r[5] << 16);
    o.w = (uint_t)r[6] | ((uint_t)r[7] << 16);
    ((uint4*)out)[(size_t)i * V + v] = o;
}

// ================= fused GEMM2+3: h = relu(t1@W1b+b1b) [LDS] ; y2 = h@W2a ==================

#define HSTRIDE 104   // 96 + 8 pad shorts

__global__ void k_mfma23(const ushort_t* __restrict__ t1, const ushort_t* __restrict__ wf,
                         const float* __restrict__ b1b, ushort_t* __restrict__ y2) {
    constexpr int KC = 3, NT1 = 6, NT2 = 2;
    __shared__ __align__(16) ushort_t hT[4][16 * HSTRIDE];
    int lane = threadIdx.x & 63;
    int widx = threadIdx.x >> 6;
    int tile = blockIdx.x * 4 + widx;
    bool live = tile < MT1;
    int row0 = tile * 16;
    int q = lane >> 4;
    int l16 = lane & 15;
    const short8* bfp1 = (const short8*)wf;
    const short8* bfp2 = (const short8*)(wf + 9216);

    if (live) {
        short8 bf[NT1][KC];
#pragma unroll
        for (int nt = 0; nt < NT1; ++nt)
#pragma unroll
            for (int c = 0; c < KC; ++c)
                bf[nt][c] = bfp1[(nt * KC + c) * 64 + lane];

        short8 af[KC];
#pragma unroll
        for (int c = 0; c < KC; ++c) {
            uint4 av = *(const uint4*)(t1 + (size_t)(row0 + l16) * DD + c * 32 + q * 8);
            af[c] = *(short8*)&av;
        }

        f32x4 acc[NT1];
#pragma unroll
        for (int nt = 0; nt < NT1; ++nt) acc[nt] = (f32x4){0.f, 0.f, 0.f, 0.f};
#pragma unroll
        for (int nt = 0; nt < NT1; ++nt)
#pragma unroll
            for (int c = 0; c < KC; ++c)
                acc[nt] = __builtin_amdgcn_mfma_f32_16x16x32_bf16(af[c], bf[nt][c], acc[nt], 0, 0, 0);

#pragma unroll
        for (int nt = 0; nt < NT1; ++nt) {
            int col = nt * 16 + l16;
            float bv = b1b[col];
#pragma unroll
            for (int r = 0; r < 4; ++r)
                hT[widx][(q * 4 + r) * HSTRIDE + col] = f2bf(fmaxf(acc[nt][r] + bv, 0.0f));
        }
    }
    __syncthreads();
    if (!live) return;

    short8 af2[KC];
#pragma unroll
    for (int c = 0; c < KC; ++c) {
        uint4 av = *(const uint4*)&hT[widx][l16 * HSTRIDE + c * 32 + q * 8];
        af2[c] = *(short8*)&av;
    }
    short8 bf2[NT2][KC];
#pragma unroll
    for (int nt = 0; nt < NT2; ++nt)
#pragma unroll
        for (int c = 0; c < KC; ++c)
            bf2[nt][c] = bfp2[(nt * KC + c) * 64 + lane];

    f32x4 acc2[NT2];
#pragma unroll
    for (int nt = 0; nt < NT2; ++nt) acc2[nt] = (f32x4){0.f, 0.f, 0.f, 0.f};
#pragma unroll
    for (int nt = 0; nt < NT2; ++nt)
#pragma unroll
        for (int c = 0; c < KC; ++c)
            acc2[nt] = __builtin_amdgcn_mfma_f32_16x16x32_bf16(af2[c], bf2[nt][c], acc2[nt], 0, 0, 0);

#pragma unroll
    for (int nt = 0; nt < NT2; ++nt) {
        int col = nt * 16 + l16;
#pragma unroll
        for (int r = 0; r < 4; ++r)
            y2[(size_t)(row0 + q * 4 + r) * HH + col] = f2bf(acc2[nt][r]);
    }
}

// ================= fused agg2 + tail: 16 rows x 16 threads (4 parts x 4 slices) =============

#define TSTRIDE 36   // 32 + 4 pad floats
#define ATR 16       // rows per block

__global__ void k_aggtail(const ushort_t* __restrict__ y2, const int* __restrict__ deg,
                          const ushort_t* __restrict__ ell, const float* __restrict__ eps_p,
                          const float* __restrict__ b2a, const float* __restrict__ W2b,
                          const float* __restrict__ b2b, const float* __restrict__ Wh,
                          const float* __restrict__ bhp, float* __restrict__ out) {
    __shared__ float t2f[ATR * TSTRIDE];
    int row = threadIdx.x >> 4;        // 0..15
    int sub = threadIdx.x & 15;
    int jg = sub & 3;                  // 16B slice
    int part = sub >> 2;               // edge partition (lane bits 2,3)
    int i = blockIdx.x * ATR + row;
    bool live = i < NN;

    if (live) {
        const uint4* y4 = (const uint4*)y2;
        const ushort_t* er = ell + (size_t)i * ELLW;
        int d = min(deg[i], ELLW);
        float a0[8] = {0,0,0,0,0,0,0,0}, a1[8] = {0,0,0,0,0,0,0,0};
        int p = part;
        for (; p + 4 < d; p += 8) {
            int s0 = er[p], s1 = er[p + 4];
            uint4 f0 = y4[(size_t)s0 * 4 + jg];
            uint4 f1 = y4[(size_t)s1 * 4 + jg];
            addbf8(a0, f0); addbf8(a1, f1);
        }
        for (; p < d; p += 4) addbf8(a0, y4[(size_t)er[p] * 4 + jg]);

        float s[8];
#pragma unroll
        for (int k = 0; k < 8; ++k) {
            s[k] = a0[k] + a1[k];
            s[k] += __shfl_xor(s[k], 4);
            s[k] += __shfl_xor(s[k], 8);
        }
        if (part == 0) {
            uint4 su = y4[(size_t)i * 4 + jg];
            float s8[8];
            s8[0] = __uint_as_float(su.x << 16); s8[1] = __uint_as_float(su.x & 0xffff0000u);
            s8[2] = __uint_as_float(su.y << 16); s8[3] = __uint_as_float(su.y & 0xffff0000u);
            s8[4] = __uint_as_float(su.z << 16); s8[5] = __uint_as_float(su.z & 0xffff0000u);
            s8[6] = __uint_as_float(su.w << 16); s8[7] = __uint_as_float(su.w & 0xffff0000u);
            float4 bl = ((const float4*)b2a)[2 * jg];
            float4 bhv = ((const float4*)b2a)[2 * jg + 1];
            float bb[8] = {bl.x, bl.y, bl.z, bl.w, bhv.x, bhv.y, bhv.z, bhv.w};
            float e = 1.0f + eps_p[0];
#pragma unroll
            for (int k = 0; k < 8; ++k) {
                float vv = fmaf(e, s8[k], s[k]) + bb[k];
                t2f[row * TSTRIDE + jg * 8 + k] = fmaxf(vv, 0.0f);
            }
        }
    }
    __syncthreads();

    float o[OO] = {0.f, 0.f, 0.f, 0.f};
    if (live) {
        const float* tr = &t2f[row * TSTRIDE];
#pragma unroll
        for (int jj = 0; jj < 2; ++jj) {
            int j = sub * 2 + jj;
            float acc = b2b[j];
#pragma unroll 8
            for (int k = 0; k < HH; ++k)
                acc = fmaf(tr[k], W2b[k * HH + j], acc);
            acc = fmaxf(acc, 0.0f);
#pragma unroll
            for (int oo = 0; oo < OO; ++oo)
                o[oo] = fmaf(acc, Wh[j * OO + oo], o[oo]);
        }
    }
#pragma unroll
    for (int oo = 0; oo < OO; ++oo) {
        o[oo] += __shfl_xor(o[oo], 1);
        o[oo] += __shfl_xor(o[oo], 2);
        o[oo] += __shfl_xor(o[oo], 4);
        o[oo] += __shfl_xor(o[oo], 8);
    }
    if (live && sub == 0) {
        float4 ov = {o[0] + bhp[0], o[1] + bhp[1], o[2] + bhp[2], o[3] + bhp[3]};
        ((float4*)out)[i] = ov;
    }
}

// ================= launch =================

extern "C" void kernel_launch(void* const* d_in, const int* in_sizes, int n_in,
                              void* d_out, int out_size, void* d_ws, size_t ws_size,
                              hipStream_t stream) {
    const float* x    = (const float*)d_in[0];
    const int*   edges= (const int*)d_in[1];
    const float* eps1 = (const float*)d_in[2];
    const float* eps2 = (const float*)d_in[3];
    const float* W1a  = (const float*)d_in[4];
    const float* b1a  = (const float*)d_in[5];
    const float* W1b  = (const float*)d_in[6];
    const float* b1b  = (const float*)d_in[7];
    const float* W2a  = (const float*)d_in[8];
    const float* b2a  = (const float*)d_in[9];
    const float* W2b  = (const float*)d_in[10];
    const float* b2b  = (const float*)d_in[11];
    const float* Wh   = (const float*)d_in[12];
    const float* bh   = (const float*)d_in[13];

    auto al = [](size_t n) { return (n + 255) / 256 * 256; };
    char* w = (char*)d_ws;
    int*      bcnt   = (int*)w;      w += al((size_t)NBUCK * 4);
    uint_t*   packed = (uint_t*)w;   w += al((size_t)NBUCK * BCAP * 4);
    int*      deg    = (int*)w;      w += al((size_t)NN * 4);
    ushort_t* ell    = (ushort_t*)w; w += al((size_t)NN * ELLW * 2);
    ushort_t* wf     = (ushort_t*)w; w += al((size_t)(9216 + 3072) * 2);
    ushort_t* y1     = (ushort_t*)w; w += al((size_t)NN * DD * 2);
    ushort_t* t1     = (ushort_t*)w; w += al((size_t)NN * DD * 2);
    ushort_t* y2     = (ushort_t*)w; w += al((size_t)NN * HH * 2);

    const int B = 256;

    hipMemsetAsync(bcnt, 0, (size_t)NBUCK * 4, stream);
    k_big1<<<BA_B + WF_B + MFMA1_B, B, 0, stream>>>(edges, bcnt, packed, W1b, W2a, wf,
                                                    x, W1a, y1);
    k_bucketB<<<NBUCK, B, 0, stream>>>(bcnt, packed, ell, deg);
    k_aggb96<<<(NN * (DD/8) * 4 + B - 1) / B, B, 0, stream>>>(y1, deg, ell, eps1, b1a, t1);
    k_mfma23<<<MFMA1_B, B, 0, stream>>>(t1, wf, b1b, y2);
    k_aggtail<<<(NN + ATR - 1) / ATR, B, 0, stream>>>(y2, deg, ell, eps2, b2a, W2b, b2b,
                                                      Wh, bh, (float*)d_out);
}

// Round 12
// 187.886 us; speedup vs baseline: 1.0971x; 1.0971x over previous
//
#include <hip/hip_runtime.h>

#define NN 50000
#define NE 800000
#define DD 96
#define HH 32
#define OO 4
#define ELLW 64            // max degree; deg ~ Poisson(16), guarded/clamped
#define NBUCK 196          // 256-node buckets
#define BCAP 8192          // per-bucket edge capacity (mean 4081)

typedef unsigned short ushort_t;
typedef unsigned int uint_t;
typedef __attribute__((ext_vector_type(8))) short short8;
typedef __attribute__((ext_vector_type(4))) float f32x4;

__device__ inline ushort_t f2bf(float f) {
    uint_t b = __float_as_uint(f);
    return (ushort_t)((b + 0x7fffu + ((b >> 16) & 1u)) >> 16);   // RNE
}

__device__ inline void addbf8(float* a, uint4 u) {
    a[0] += __uint_as_float(u.x << 16);
    a[1] += __uint_as_float(u.x & 0xffff0000u);
    a[2] += __uint_as_float(u.y << 16);
    a[3] += __uint_as_float(u.y & 0xffff0000u);
    a[4] += __uint_as_float(u.z << 16);
    a[5] += __uint_as_float(u.z & 0xffff0000u);
    a[6] += __uint_as_float(u.w << 16);
    a[7] += __uint_as_float(u.w & 0xffff0000u);
}

// ================= k1: edge bucketing (A, 8192 edges/block) | W frags | y1 = x@W1a (slabbed) =

#define BA_B   98                            // ceil(200000 quads / 2048)
#define WF_B   6                             // 1152 (W1b) + 384 (W2a) frag-threads
#define MT1    (NN / 16)                     // 3125 M tiles
#define MFMA1_B ((MT1 + 3) / 4)              // 782

__global__ void k_big1(const int* __restrict__ edges, int* __restrict__ bcnt,
                       uint_t* __restrict__ packed,
                       const float* __restrict__ W1b, const float* __restrict__ W2a,
                       ushort_t* __restrict__ wf,
                       const float* __restrict__ x, const float* __restrict__ W1a,
                       ushort_t* __restrict__ y1) {
    int b = blockIdx.x;
    if (b < BA_B) {
        __shared__ int hist[NBUCK];
        __shared__ int basesh[NBUCK];
        int thr = threadIdx.x;
        if (thr < NBUCK) hist[thr] = 0;
        __syncthreads();
#pragma unroll
        for (int k = 0; k < 8; ++k) {
            int t4 = b * 2048 + k * 256 + thr;
            if (t4 < NE / 4) {
                int4 tt = ((const int4*)(edges + NE))[t4];
                atomicAdd(&hist[tt.x >> 8], 1);
                atomicAdd(&hist[tt.y >> 8], 1);
                atomicAdd(&hist[tt.z >> 8], 1);
                atomicAdd(&hist[tt.w >> 8], 1);
            }
        }
        __syncthreads();
        if (thr < NBUCK) {
            int c = hist[thr];
            basesh[thr] = c ? atomicAdd(&bcnt[thr], c) : 0;
        }
        __syncthreads();
        if (thr < NBUCK) hist[thr] = 0;
        __syncthreads();
#pragma unroll
        for (int k = 0; k < 8; ++k) {
            int t4 = b * 2048 + k * 256 + thr;
            if (t4 < NE / 4) {
                int4 ss = ((const int4*)edges)[t4];
                int4 tt = ((const int4*)(edges + NE))[t4];
                int b0 = tt.x >> 8, b1 = tt.y >> 8, b2 = tt.z >> 8, b3 = tt.w >> 8;
                int p0 = basesh[b0] + atomicAdd(&hist[b0], 1);
                int p1 = basesh[b1] + atomicAdd(&hist[b1], 1);
                int p2 = basesh[b2] + atomicAdd(&hist[b2], 1);
                int p3 = basesh[b3] + atomicAdd(&hist[b3], 1);
                if (p0 < BCAP) packed[(size_t)b0 * BCAP + p0] = ((uint_t)ss.x << 8) | (tt.x & 255);
                if (p1 < BCAP) packed[(size_t)b1 * BCAP + p1] = ((uint_t)ss.y << 8) | (tt.y & 255);
                if (p2 < BCAP) packed[(size_t)b2 * BCAP + p2] = ((uint_t)ss.z << 8) | (tt.z & 255);
                if (p3 < BCAP) packed[(size_t)b3 * BCAP + p3] = ((uint_t)ss.w << 8) | (tt.w & 255);
            }
        }
        return;
    }
    b -= BA_B;
    if (b < WF_B) {
        int tw = b * 256 + threadIdx.x;
        if (tw < 1152 + 384) {
            const float* Wsrc; ushort_t* dst; int KOUT, fl;
            if (tw < 1152) { Wsrc = W1b; dst = wf;        KOUT = DD; fl = tw; }
            else           { Wsrc = W2a; dst = wf + 9216; KOUT = HH; fl = tw - 1152; }
            int lane = fl & 63;
            int fc = fl >> 6;
            int c = fc % 3, nt = fc / 3;
            int kb = c * 32 + (lane >> 4) * 8;
            int col = nt * 16 + (lane & 15);
            ushort_t v[8];
#pragma unroll
            for (int j = 0; j < 8; ++j)
                v[j] = f2bf(Wsrc[(size_t)(kb + j) * KOUT + col]);
            *(uint4*)(dst + (size_t)fl * 8) = *(uint4*)v;
        }
        return;
    }
    b -= WF_B;
    // ---- mfma1: y1 = x @ W1a, epilogue writes 3 column-slabs [NN][32] ----
    constexpr int KC = 3, NT = 6;
    int lane = threadIdx.x & 63;
    int widx = threadIdx.x >> 6;
    int tile = b * 4 + widx;
    if (tile >= MT1) return;
    int row0 = tile * 16;
    int q = lane >> 4;
    int l16 = lane & 15;

    short8 bf[NT][KC];
#pragma unroll
    for (int nt = 0; nt < NT; ++nt)
#pragma unroll
        for (int c = 0; c < KC; ++c) {
            ushort_t v[8];
#pragma unroll
            for (int j = 0; j < 8; ++j)
                v[j] = f2bf(W1a[(size_t)(c * 32 + q * 8 + j) * DD + nt * 16 + l16]);
            bf[nt][c] = *(short8*)v;
        }

    short8 af[KC];
#pragma unroll
    for (int c = 0; c < KC; ++c) {
        const float* ap = x + (size_t)(row0 + l16) * DD + c * 32 + q * 8;
        float4 f0 = *(const float4*)ap;
        float4 f1 = *(const float4*)(ap + 4);
        ushort_t v[8] = {f2bf(f0.x), f2bf(f0.y), f2bf(f0.z), f2bf(f0.w),
                         f2bf(f1.x), f2bf(f1.y), f2bf(f1.z), f2bf(f1.w)};
        af[c] = *(short8*)v;
    }

    f32x4 acc[NT];
#pragma unroll
    for (int nt = 0; nt < NT; ++nt) acc[nt] = (f32x4){0.f, 0.f, 0.f, 0.f};
#pragma unroll
    for (int nt = 0; nt < NT; ++nt)
#pragma unroll
        for (int c = 0; c < KC; ++c)
            acc[nt] = __builtin_amdgcn_mfma_f32_16x16x32_bf16(af[c], bf[nt][c], acc[nt], 0, 0, 0);

#pragma unroll
    for (int nt = 0; nt < NT; ++nt) {
        int s = nt >> 1;
        int c32 = (nt & 1) * 16 + l16;
#pragma unroll
        for (int r = 0; r < 4; ++r)
            y1[(size_t)s * NN * 32 + (size_t)(row0 + q * 4 + r) * 32 + c32] = f2bf(acc[nt][r]);
    }
}

// ================= phase B: per-bucket ELL fill via LDS counters (256-node buckets) =========

__global__ void k_bucketB(const int* __restrict__ bcnt, const uint_t* __restrict__ packed,
                          ushort_t* __restrict__ ell, int* __restrict__ deg) {
    __shared__ int curL[256];
    int b = blockIdx.x;
    int thr = threadIdx.x;
    int n0 = b * 256;
    curL[thr] = 0;
    __syncthreads();
    int cnt = min(bcnt[b], BCAP);
    const uint_t* pk = packed + (size_t)b * BCAP;
    for (int e = thr; e < cnt; e += 256) {
        uint_t u = pk[e];
        int doff = u & 255;
        int src = u >> 8;
        int p = atomicAdd(&curL[doff], 1);
        if (p < ELLW) ell[(size_t)(n0 + doff) * ELLW + p] = (ushort_t)src;
    }
    __syncthreads();
    if (n0 + thr < NN) deg[n0 + thr] = curL[thr];
}

// ================= agg layer 1 over slabbed y1: slab-major task order, 2-way edge split =====
// task: idx = s*(NN*8) + i*8 + v*2 + part;  y1 slab s = [NN][32] bf16 at y1 + s*NN*32.

__global__ void k_aggb96(const ushort_t* __restrict__ y, const int* __restrict__ deg,
                         const ushort_t* __restrict__ ell, const float* __restrict__ eps_p,
                         const float* __restrict__ b, ushort_t* __restrict__ out) {
    int idx = blockIdx.x * blockDim.x + threadIdx.x;
    if (idx >= NN * 24) return;
    int s = idx / (NN * 8);
    int rem = idx - s * (NN * 8);
    int i = rem >> 3;
    int sub = rem & 7;
    int v = sub >> 1, part = sub & 1;
    const uint4* ys = (const uint4*)(y + (size_t)s * NN * 32);   // row = 4 uint4
    const ushort_t* er = ell + (size_t)i * ELLW;
    int d = min(deg[i], ELLW);
    float a0[8] = {0,0,0,0,0,0,0,0}, a1[8] = {0,0,0,0,0,0,0,0};
    float a2[8] = {0,0,0,0,0,0,0,0}, a3[8] = {0,0,0,0,0,0,0,0};
    int p = part;
    for (; p + 6 < d; p += 8) {
        int s0 = er[p], s1 = er[p+2], s2 = er[p+4], s3 = er[p+6];
        uint4 f0 = ys[(size_t)s0 * 4 + v];
        uint4 f1 = ys[(size_t)s1 * 4 + v];
        uint4 f2 = ys[(size_t)s2 * 4 + v];
        uint4 f3 = ys[(size_t)s3 * 4 + v];
        addbf8(a0, f0); addbf8(a1, f1); addbf8(a2, f2); addbf8(a3, f3);
    }
    for (; p < d; p += 2) addbf8(a0, ys[(size_t)er[p] * 4 + v]);

    float sm[8];
#pragma unroll
    for (int k = 0; k < 8; ++k) {
        sm[k] = (a0[k] + a1[k]) + (a2[k] + a3[k]);
        sm[k] += __shfl_xor(sm[k], 1);          // combine parts (adjacent lanes)
    }
    if (part) return;

    uint4 su = ys[(size_t)i * 4 + v];
    float s8[8];
    s8[0] = __uint_as_float(su.x << 16); s8[1] = __uint_as_float(su.x & 0xffff0000u);
    s8[2] = __uint_as_float(su.y << 16); s8[3] = __uint_as_float(su.y & 0xffff0000u);
    s8[4] = __uint_as_float(su.z << 16); s8[5] = __uint_as_float(su.z & 0xffff0000u);
    s8[6] = __uint_as_float(su.w << 16); s8[7] = __uint_as_float(su.w & 0xffff0000u);
    float4 bl = ((const float4*)b)[s * 8 + v * 2];
    float4 bhv = ((const float4*)b)[s * 8 + v * 2 + 1];
    float bb[8] = {bl.x, bl.y, bl.z, bl.w, bhv.x, bhv.y, bhv.z, bhv.w};
    float e = 1.0f + eps_p[0];
    ushort_t r[8];
#pragma unroll
    for (int k = 0; k < 8; ++k) {
        float vv = fmaf(e, s8[k], sm[k]) + bb[k];
        r[k] = f2bf(fmaxf(vv, 0.0f));
    }
    uint4 o;
    o.x = (uint_t)r[0] | ((uint_t)r[1] << 16);
    o.y = (uint_t)r[2] | ((uint_t)r[3] << 16);
    o.z = (uint_t)r[4] | ((uint_t)r[5] << 16);
    o.w = (uint_t)r[6] | ((uint_t)r[7] << 16);
    ((uint4*)out)[(size_t)i * 12 + s * 4 + v] = o;   // t1 row-major
}

// ================= fused GEMM2+3: h = relu(t1@W1b+b1b) [LDS] ; y2 = h@W2a ==================

#define HSTRIDE 104   // 96 + 8 pad shorts

__global__ void k_mfma23(const ushort_t* __restrict__ t1, const ushort_t* __restrict__ wf,
                         const float* __restrict__ b1b, ushort_t* __restrict__ y2) {
    constexpr int KC = 3, NT1 = 6, NT2 = 2;
    __shared__ __align__(16) ushort_t hT[4][16 * HSTRIDE];
    int lane = threadIdx.x & 63;
    int widx = threadIdx.x >> 6;
    int tile = blockIdx.x * 4 + widx;
    bool live = tile < MT1;
    int row0 = tile * 16;
    int q = lane >> 4;
    int l16 = lane & 15;
    const short8* bfp1 = (const short8*)wf;
    const short8* bfp2 = (const short8*)(wf + 9216);

    if (live) {
        short8 bf[NT1][KC];
#pragma unroll
        for (int nt = 0; nt < NT1; ++nt)
#pragma unroll
            for (int c = 0; c < KC; ++c)
                bf[nt][c] = bfp1[(nt * KC + c) * 64 + lane];

        short8 af[KC];
#pragma unroll
        for (int c = 0; c < KC; ++c) {
            uint4 av = *(const uint4*)(t1 + (size_t)(row0 + l16) * DD + c * 32 + q * 8);
            af[c] = *(short8*)&av;
        }

        f32x4 acc[NT1];
#pragma unroll
        for (int nt = 0; nt < NT1; ++nt) acc[nt] = (f32x4){0.f, 0.f, 0.f, 0.f};
#pragma unroll
        for (int nt = 0; nt < NT1; ++nt)
#pragma unroll
            for (int c = 0; c < KC; ++c)
                acc[nt] = __builtin_amdgcn_mfma_f32_16x16x32_bf16(af[c], bf[nt][c], acc[nt], 0, 0, 0);

#pragma unroll
        for (int nt = 0; nt < NT1; ++nt) {
            int col = nt * 16 + l16;
            float bv = b1b[col];
#pragma unroll
            for (int r = 0; r < 4; ++r)
                hT[widx][(q * 4 + r) * HSTRIDE + col] = f2bf(fmaxf(acc[nt][r] + bv, 0.0f));
        }
    }
    __syncthreads();
    if (!live) return;

    short8 af2[KC];
#pragma unroll
    for (int c = 0; c < KC; ++c) {
        uint4 av = *(const uint4*)&hT[widx][l16 * HSTRIDE + c * 32 + q * 8];
        af2[c] = *(short8*)&av;
    }
    short8 bf2[NT2][KC];
#pragma unroll
    for (int nt = 0; nt < NT2; ++nt)
#pragma unroll
        for (int c = 0; c < KC; ++c)
            bf2[nt][c] = bfp2[(nt * KC + c) * 64 + lane];

    f32x4 acc2[NT2];
#pragma unroll
    for (int nt = 0; nt < NT2; ++nt) acc2[nt] = (f32x4){0.f, 0.f, 0.f, 0.f};
#pragma unroll
    for (int nt = 0; nt < NT2; ++nt)
#pragma unroll
        for (int c = 0; c < KC; ++c)
            acc2[nt] = __builtin_amdgcn_mfma_f32_16x16x32_bf16(af2[c], bf2[nt][c], acc2[nt], 0, 0, 0);

#pragma unroll
    for (int nt = 0; nt < NT2; ++nt) {
        int col = nt * 16 + l16;
#pragma unroll
        for (int r = 0; r < 4; ++r)
            y2[(size_t)(row0 + q * 4 + r) * HH + col] = f2bf(acc2[nt][r]);
    }
}

// ================= fused agg2 + tail: 16 rows x 16 threads (4 parts x 4 slices) =============

#define TSTRIDE 36   // 32 + 4 pad floats
#define ATR 16       // rows per block

__global__ void k_aggtail(const ushort_t* __restrict__ y2, const int* __restrict__ deg,
                          const ushort_t* __restrict__ ell, const float* __restrict__ eps_p,
                          const float* __restrict__ b2a, const float* __restrict__ W2b,
                          const float* __restrict__ b2b, const float* __restrict__ Wh,
                          const float* __restrict__ bhp, float* __restrict__ out) {
    __shared__ float t2f[ATR * TSTRIDE];
    int row = threadIdx.x >> 4;        // 0..15
    int sub = threadIdx.x & 15;
    int jg = sub & 3;                  // 16B slice
    int part = sub >> 2;               // edge partition (lane bits 2,3)
    int i = blockIdx.x * ATR + row;
    bool live = i < NN;

    if (live) {
        const uint4* y4 = (const uint4*)y2;
        const ushort_t* er = ell + (size_t)i * ELLW;
        int d = min(deg[i], ELLW);
        float a0[8] = {0,0,0,0,0,0,0,0}, a1[8] = {0,0,0,0,0,0,0,0};
        int p = part;
        for (; p + 4 < d; p += 8) {
            int s0 = er[p], s1 = er[p + 4];
            uint4 f0 = y4[(size_t)s0 * 4 + jg];
            uint4 f1 = y4[(size_t)s1 * 4 + jg];
            addbf8(a0, f0); addbf8(a1, f1);
        }
        for (; p < d; p += 4) addbf8(a0, y4[(size_t)er[p] * 4 + jg]);

        float s[8];
#pragma unroll
        for (int k = 0; k < 8; ++k) {
            s[k] = a0[k] + a1[k];
            s[k] += __shfl_xor(s[k], 4);
            s[k] += __shfl_xor(s[k], 8);
        }
        if (part == 0) {
            uint4 su = y4[(size_t)i * 4 + jg];
            float s8[8];
            s8[0] = __uint_as_float(su.x << 16); s8[1] = __uint_as_float(su.x & 0xffff0000u);
            s8[2] = __uint_as_float(su.y << 16); s8[3] = __uint_as_float(su.y & 0xffff0000u);
            s8[4] = __uint_as_float(su.z << 16); s8[5] = __uint_as_float(su.z & 0xffff0000u);
            s8[6] = __uint_as_float(su.w << 16); s8[7] = __uint_as_float(su.w & 0xffff0000u);
            float4 bl = ((const float4*)b2a)[2 * jg];
            float4 bhv = ((const float4*)b2a)[2 * jg + 1];
            float bb[8] = {bl.x, bl.y, bl.z, bl.w, bhv.x, bhv.y, bhv.z, bhv.w};
            float e = 1.0f + eps_p[0];
#pragma unroll
            for (int k = 0; k < 8; ++k) {
                float vv = fmaf(e, s8[k], s[k]) + bb[k];
                t2f[row * TSTRIDE + jg * 8 + k] = fmaxf(vv, 0.0f);
            }
        }
    }
    __syncthreads();

    float o[OO] = {0.f, 0.f, 0.f, 0.f};
    if (live) {
        const float* tr = &t2f[row * TSTRIDE];
#pragma unroll
        for (int jj = 0; jj < 2; ++jj) {
            int j = sub * 2 + jj;
            float acc = b2b[j];
#pragma unroll 8
            for (int k = 0; k < HH; ++k)
                acc = fmaf(tr[k], W2b[k * HH + j], acc);
            acc = fmaxf(acc, 0.0f);
#pragma unroll
            for (int oo = 0; oo < OO; ++oo)
                o[oo] = fmaf(acc, Wh[j * OO + oo], o[oo]);
        }
    }
#pragma unroll
    for (int oo = 0; oo < OO; ++oo) {
        o[oo] += __shfl_xor(o[oo], 1);
        o[oo] += __shfl_xor(o[oo], 2);
        o[oo] += __shfl_xor(o[oo], 4);
        o[oo] += __shfl_xor(o[oo], 8);
    }
    if (live && sub == 0) {
        float4 ov = {o[0] + bhp[0], o[1] + bhp[1], o[2] + bhp[2], o[3] + bhp[3]};
        ((float4*)out)[i] = ov;
    }
}

// ================= launch =================

extern "C" void kernel_launch(void* const* d_in, const int* in_sizes, int n_in,
                              void* d_out, int out_size, void* d_ws, size_t ws_size,
                              hipStream_t stream) {
    const float* x    = (const float*)d_in[0];
    const int*   edges= (const int*)d_in[1];
    const float* eps1 = (const float*)d_in[2];
    const float* eps2 = (const float*)d_in[3];
    const float* W1a  = (const float*)d_in[4];
    const float* b1a  = (const float*)d_in[5];
    const float* W1b  = (const float*)d_in[6];
    const float* b1b  = (const float*)d_in[7];
    const float* W2a  = (const float*)d_in[8];
    const float* b2a  = (const float*)d_in[9];
    const float* W2b  = (const float*)d_in[10];
    const float* b2b  = (const float*)d_in[11];
    const float* Wh   = (const float*)d_in[12];
    const float* bh   = (const float*)d_in[13];

    auto al = [](size_t n) { return (n + 255) / 256 * 256; };
    char* w = (char*)d_ws;
    int*      bcnt   = (int*)w;      w += al((size_t)NBUCK * 4);
    uint_t*   packed = (uint_t*)w;   w += al((size_t)NBUCK * BCAP * 4);
    int*      deg    = (int*)w;      w += al((size_t)NN * 4);
    ushort_t* ell    = (ushort_t*)w; w += al((size_t)NN * ELLW * 2);
    ushort_t* wf     = (ushort_t*)w; w += al((size_t)(9216 + 3072) * 2);
    ushort_t* y1     = (ushort_t*)w; w += al((size_t)NN * DD * 2);   // 3 slabs of [NN][32]
    ushort_t* t1     = (ushort_t*)w; w += al((size_t)NN * DD * 2);
    ushort_t* y2     = (ushort_t*)w; w += al((size_t)NN * HH * 2);

    const int B = 256;

    hipMemsetAsync(bcnt, 0, (size_t)NBUCK * 4, stream);
    k_big1<<<BA_B + WF_B + MFMA1_B, B, 0, stream>>>(edges, bcnt, packed, W1b, W2a, wf,
                                                    x, W1a, y1);
    k_bucketB<<<NBUCK, B, 0, stream>>>(bcnt, packed, ell, deg);
    k_aggb96<<<(NN * 24 + B - 1) / B, B, 0, stream>>>(y1, deg, ell, eps1, b1a, t1);
    k_mfma23<<<MFMA1_B, B, 0, stream>>>(t1, wf, b1b, y2);
    k_aggtail<<<(NN + ATR - 1) / ATR, B, 0, stream>>>(y2, deg, ell, eps2, b2a, W2b, b2b,
                                                      Wh, bh, (float*)d_out);
}

// Round 13
// 181.350 us; speedup vs baseline: 1.1367x; 1.0360x over previous
//
#include <hip/hip_runtime.h>

#define NN 50000
#define NE 800000
#define DD 96
#define HH 32
#define OO 4
#define ELLW 64            // max degree; deg ~ Poisson(16), guarded/clamped
#define NBUCK 196          // 256-node buckets
#define BCAP 8192          // per-bucket edge capacity (mean 4081)

typedef unsigned short ushort_t;
typedef unsigned int uint_t;
typedef __attribute__((ext_vector_type(8))) short short8;
typedef __attribute__((ext_vector_type(4))) float f32x4;

__device__ inline ushort_t f2bf(float f) {
    uint_t b = __float_as_uint(f);
    return (ushort_t)((b + 0x7fffu + ((b >> 16) & 1u)) >> 16);   // RNE
}

__device__ inline void addbf8(float* a, uint4 u) {
    a[0] += __uint_as_float(u.x << 16);
    a[1] += __uint_as_float(u.x & 0xffff0000u);
    a[2] += __uint_as_float(u.y << 16);
    a[3] += __uint_as_float(u.y & 0xffff0000u);
    a[4] += __uint_as_float(u.z << 16);
    a[5] += __uint_as_float(u.z & 0xffff0000u);
    a[6] += __uint_as_float(u.w << 16);
    a[7] += __uint_as_float(u.w & 0xffff0000u);
}

// ================= k_pre: edge bucketing phase A | W1b/W2a frag swizzle ====================

#define BA_B   196                           // 4096 edges (1024 quads) per block
#define WF_B   6                             // 1152 (W1b) + 384 (W2a) frag-threads

__global__ void k_pre(const int* __restrict__ edges, int* __restrict__ bcnt,
                      uint_t* __restrict__ packed,
                      const float* __restrict__ W1b, const float* __restrict__ W2a,
                      ushort_t* __restrict__ wf) {
    int b = blockIdx.x;
    if (b < BA_B) {
        __shared__ int hist[NBUCK];
        __shared__ int basesh[NBUCK];
        int thr = threadIdx.x;
        if (thr < NBUCK) hist[thr] = 0;
        __syncthreads();
#pragma unroll
        for (int k = 0; k < 4; ++k) {
            int t4 = b * 1024 + k * 256 + thr;
            if (t4 < NE / 4) {
                int4 tt = ((const int4*)(edges + NE))[t4];
                atomicAdd(&hist[tt.x >> 8], 1);
                atomicAdd(&hist[tt.y >> 8], 1);
                atomicAdd(&hist[tt.z >> 8], 1);
                atomicAdd(&hist[tt.w >> 8], 1);
            }
        }
        __syncthreads();
        if (thr < NBUCK) {
            int c = hist[thr];
            basesh[thr] = c ? atomicAdd(&bcnt[thr], c) : 0;
        }
        __syncthreads();
        if (thr < NBUCK) hist[thr] = 0;
        __syncthreads();
#pragma unroll
        for (int k = 0; k < 4; ++k) {
            int t4 = b * 1024 + k * 256 + thr;
            if (t4 < NE / 4) {
                int4 ss = ((const int4*)edges)[t4];
                int4 tt = ((const int4*)(edges + NE))[t4];
                int b0 = tt.x >> 8, b1 = tt.y >> 8, b2 = tt.z >> 8, b3 = tt.w >> 8;
                int p0 = basesh[b0] + atomicAdd(&hist[b0], 1);
                int p1 = basesh[b1] + atomicAdd(&hist[b1], 1);
                int p2 = basesh[b2] + atomicAdd(&hist[b2], 1);
                int p3 = basesh[b3] + atomicAdd(&hist[b3], 1);
                if (p0 < BCAP) packed[(size_t)b0 * BCAP + p0] = ((uint_t)ss.x << 8) | (tt.x & 255);
                if (p1 < BCAP) packed[(size_t)b1 * BCAP + p1] = ((uint_t)ss.y << 8) | (tt.y & 255);
                if (p2 < BCAP) packed[(size_t)b2 * BCAP + p2] = ((uint_t)ss.z << 8) | (tt.z & 255);
                if (p3 < BCAP) packed[(size_t)b3 * BCAP + p3] = ((uint_t)ss.w << 8) | (tt.w & 255);
            }
        }
        return;
    }
    b -= BA_B;
    int tw = b * 256 + threadIdx.x;
    if (tw < 1152 + 384) {
        const float* Wsrc; ushort_t* dst; int KOUT, fl;
        if (tw < 1152) { Wsrc = W1b; dst = wf;        KOUT = DD; fl = tw; }
        else           { Wsrc = W2a; dst = wf + 9216; KOUT = HH; fl = tw - 1152; }
        int lane = fl & 63;
        int fc = fl >> 6;
        int c = fc % 3, nt = fc / 3;
        int kb = c * 32 + (lane >> 4) * 8;
        int col = nt * 16 + (lane & 15);
        ushort_t v[8];
#pragma unroll
        for (int j = 0; j < 8; ++j)
            v[j] = f2bf(Wsrc[(size_t)(kb + j) * KOUT + col]);
        *(uint4*)(dst + (size_t)fl * 8) = *(uint4*)v;
    }
}

// ================= k_main: bucketB (ELL fill) | mfma1 (y1 = x@W1a, LDS-staged W frags) ======

#define MT1    (NN / 16)                     // 3125 M tiles
#define MFMA1_B ((MT1 + 3) / 4)              // 782

__global__ void k_main(const int* __restrict__ bcnt, const uint_t* __restrict__ packed,
                       ushort_t* __restrict__ ell, int* __restrict__ deg,
                       const float* __restrict__ x, const float* __restrict__ W1a,
                       ushort_t* __restrict__ y1) {
    __shared__ __align__(16) ushort_t lds[1152 * 8];   // 18 KB: W1a frags / bucketB counters
    int b = blockIdx.x;
    int thr = threadIdx.x;
    if (b < NBUCK) {
        int* curL = (int*)lds;
        int n0 = b * 256;
        curL[thr] = 0;
        __syncthreads();
        int cnt = min(bcnt[b], BCAP);
        const uint_t* pk = packed + (size_t)b * BCAP;
        for (int e = thr; e < cnt; e += 256) {
            uint_t u = pk[e];
            int doff = u & 255;
            int src = u >> 8;
            int p = atomicAdd(&curL[doff], 1);
            if (p < ELLW) ell[(size_t)(n0 + doff) * ELLW + p] = (ushort_t)src;
        }
        __syncthreads();
        if (n0 + thr < NN) deg[n0 + thr] = curL[thr];
        return;
    }
    b -= NBUCK;
    // ---- mfma1: cooperative W1a->frag LDS build, then 4 waves x 16-row tiles ----
    constexpr int KC = 3, NT = 6;
    for (int fl = thr; fl < 1152; fl += 256) {
        int lane_f = fl & 63;
        int fc = fl >> 6;                    // nt*3 + c
        int c = fc % 3, nt = fc / 3;
        int kb = c * 32 + (lane_f >> 4) * 8;
        int col = nt * 16 + (lane_f & 15);
        ushort_t v[8];
#pragma unroll
        for (int j = 0; j < 8; ++j)
            v[j] = f2bf(W1a[(size_t)(kb + j) * DD + col]);
        *(uint4*)(lds + (size_t)fl * 8) = *(uint4*)v;
    }
    __syncthreads();

    int lane = thr & 63;
    int widx = thr >> 6;
    int tile = b * 4 + widx;
    if (tile >= MT1) return;
    int row0 = tile * 16;
    int q = lane >> 4;
    int l16 = lane & 15;

    short8 bf[NT][KC];
#pragma unroll
    for (int nt = 0; nt < NT; ++nt)
#pragma unroll
        for (int c = 0; c < KC; ++c)
            bf[nt][c] = *(short8*)(lds + ((size_t)(nt * 3 + c) * 64 + lane) * 8);

    short8 af[KC];
#pragma unroll
    for (int c = 0; c < KC; ++c) {
        const float* ap = x + (size_t)(row0 + l16) * DD + c * 32 + q * 8;
        float4 f0 = *(const float4*)ap;
        float4 f1 = *(const float4*)(ap + 4);
        ushort_t v[8] = {f2bf(f0.x), f2bf(f0.y), f2bf(f0.z), f2bf(f0.w),
                         f2bf(f1.x), f2bf(f1.y), f2bf(f1.z), f2bf(f1.w)};
        af[c] = *(short8*)v;
    }

    f32x4 acc[NT];
#pragma unroll
    for (int nt = 0; nt < NT; ++nt) acc[nt] = (f32x4){0.f, 0.f, 0.f, 0.f};
#pragma unroll
    for (int nt = 0; nt < NT; ++nt)
#pragma unroll
        for (int c = 0; c < KC; ++c)
            acc[nt] = __builtin_amdgcn_mfma_f32_16x16x32_bf16(af[c], bf[nt][c], acc[nt], 0, 0, 0);

    // epilogue: 3 column-slabs [NN][32]
#pragma unroll
    for (int nt = 0; nt < NT; ++nt) {
        int s = nt >> 1;
        int c32 = (nt & 1) * 16 + l16;
#pragma unroll
        for (int r = 0; r < 4; ++r)
            y1[(size_t)s * NN * 32 + (size_t)(row0 + q * 4 + r) * 32 + c32] = f2bf(acc[nt][r]);
    }
}

// ================= agg layer 1 over slabbed y1: slab-major task order, 2-way edge split =====

__global__ void k_aggb96(const ushort_t* __restrict__ y, const int* __restrict__ deg,
                         const ushort_t* __restrict__ ell, const float* __restrict__ eps_p,
                         const float* __restrict__ b, ushort_t* __restrict__ out) {
    int idx = blockIdx.x * blockDim.x + threadIdx.x;
    if (idx >= NN * 24) return;
    int s = idx / (NN * 8);
    int rem = idx - s * (NN * 8);
    int i = rem >> 3;
    int sub = rem & 7;
    int v = sub >> 1, part = sub & 1;
    const uint4* ys = (const uint4*)(y + (size_t)s * NN * 32);
    const ushort_t* er = ell + (size_t)i * ELLW;
    int d = min(deg[i], ELLW);
    float a0[8] = {0,0,0,0,0,0,0,0}, a1[8] = {0,0,0,0,0,0,0,0};
    float a2[8] = {0,0,0,0,0,0,0,0}, a3[8] = {0,0,0,0,0,0,0,0};
    int p = part;
    for (; p + 6 < d; p += 8) {
        int s0 = er[p], s1 = er[p+2], s2 = er[p+4], s3 = er[p+6];
        uint4 f0 = ys[(size_t)s0 * 4 + v];
        uint4 f1 = ys[(size_t)s1 * 4 + v];
        uint4 f2 = ys[(size_t)s2 * 4 + v];
        uint4 f3 = ys[(size_t)s3 * 4 + v];
        addbf8(a0, f0); addbf8(a1, f1); addbf8(a2, f2); addbf8(a3, f3);
    }
    for (; p < d; p += 2) addbf8(a0, ys[(size_t)er[p] * 4 + v]);

    float sm[8];
#pragma unroll
    for (int k = 0; k < 8; ++k) {
        sm[k] = (a0[k] + a1[k]) + (a2[k] + a3[k]);
        sm[k] += __shfl_xor(sm[k], 1);
    }
    if (part) return;

    uint4 su = ys[(size_t)i * 4 + v];
    float s8[8];
    s8[0] = __uint_as_float(su.x << 16); s8[1] = __uint_as_float(su.x & 0xffff0000u);
    s8[2] = __uint_as_float(su.y << 16); s8[3] = __uint_as_float(su.y & 0xffff0000u);
    s8[4] = __uint_as_float(su.z << 16); s8[5] = __uint_as_float(su.z & 0xffff0000u);
    s8[6] = __uint_as_float(su.w << 16); s8[7] = __uint_as_float(su.w & 0xffff0000u);
    float4 bl = ((const float4*)b)[s * 8 + v * 2];
    float4 bhv = ((const float4*)b)[s * 8 + v * 2 + 1];
    float bb[8] = {bl.x, bl.y, bl.z, bl.w, bhv.x, bhv.y, bhv.z, bhv.w};
    float e = 1.0f + eps_p[0];
    ushort_t r[8];
#pragma unroll
    for (int k = 0; k < 8; ++k) {
        float vv = fmaf(e, s8[k], sm[k]) + bb[k];
        r[k] = f2bf(fmaxf(vv, 0.0f));
    }
    uint4 o;
    o.x = (uint_t)r[0] | ((uint_t)r[1] << 16);
    o.y = (uint_t)r[2] | ((uint_t)r[3] << 16);
    o.z = (uint_t)r[4] | ((uint_t)r[5] << 16);
    o.w = (uint_t)r[6] | ((uint_t)r[7] << 16);
    ((uint4*)out)[(size_t)i * 12 + s * 4 + v] = o;   // t1 row-major
}

// ================= fused GEMM2+3: h = relu(t1@W1b+b1b) [LDS] ; y2 = h@W2a ==================

#define HSTRIDE 104   // 96 + 8 pad shorts

__global__ void k_mfma23(const ushort_t* __restrict__ t1, const ushort_t* __restrict__ wf,
                         const float* __restrict__ b1b, ushort_t* __restrict__ y2) {
    constexpr int KC = 3, NT1 = 6, NT2 = 2;
    __shared__ __align__(16) ushort_t hT[4][16 * HSTRIDE];
    int lane = threadIdx.x & 63;
    int widx = threadIdx.x >> 6;
    int tile = blockIdx.x * 4 + widx;
    bool live = tile < MT1;
    int row0 = tile * 16;
    int q = lane >> 4;
    int l16 = lane & 15;
    const short8* bfp1 = (const short8*)wf;
    const short8* bfp2 = (const short8*)(wf + 9216);

    if (live) {
        short8 bf[NT1][KC];
#pragma unroll
        for (int nt = 0; nt < NT1; ++nt)
#pragma unroll
            for (int c = 0; c < KC; ++c)
                bf[nt][c] = bfp1[(nt * KC + c) * 64 + lane];

        short8 af[KC];
#pragma unroll
        for (int c = 0; c < KC; ++c) {
            uint4 av = *(const uint4*)(t1 + (size_t)(row0 + l16) * DD + c * 32 + q * 8);
            af[c] = *(short8*)&av;
        }

        f32x4 acc[NT1];
#pragma unroll
        for (int nt = 0; nt < NT1; ++nt) acc[nt] = (f32x4){0.f, 0.f, 0.f, 0.f};
#pragma unroll
        for (int nt = 0; nt < NT1; ++nt)
#pragma unroll
            for (int c = 0; c < KC; ++c)
                acc[nt] = __builtin_amdgcn_mfma_f32_16x16x32_bf16(af[c], bf[nt][c], acc[nt], 0, 0, 0);

#pragma unroll
        for (int nt = 0; nt < NT1; ++nt) {
            int col = nt * 16 + l16;
            float bv = b1b[col];
#pragma unroll
            for (int r = 0; r < 4; ++r)
                hT[widx][(q * 4 + r) * HSTRIDE + col] = f2bf(fmaxf(acc[nt][r] + bv, 0.0f));
        }
    }
    __syncthreads();
    if (!live) return;

    short8 af2[KC];
#pragma unroll
    for (int c = 0; c < KC; ++c) {
        uint4 av = *(const uint4*)&hT[widx][l16 * HSTRIDE + c * 32 + q * 8];
        af2[c] = *(short8*)&av;
    }
    short8 bf2[NT2][KC];
#pragma unroll
    for (int nt = 0; nt < NT2; ++nt)
#pragma unroll
        for (int c = 0; c < KC; ++c)
            bf2[nt][c] = bfp2[(nt * KC + c) * 64 + lane];

    f32x4 acc2[NT2];
#pragma unroll
    for (int nt = 0; nt < NT2; ++nt) acc2[nt] = (f32x4){0.f, 0.f, 0.f, 0.f};
#pragma unroll
    for (int nt = 0; nt < NT2; ++nt)
#pragma unroll
        for (int c = 0; c < KC; ++c)
            acc2[nt] = __builtin_amdgcn_mfma_f32_16x16x32_bf16(af2[c], bf2[nt][c], acc2[nt], 0, 0, 0);

#pragma unroll
    for (int nt = 0; nt < NT2; ++nt) {
        int col = nt * 16 + l16;
#pragma unroll
        for (int r = 0; r < 4; ++r)
            y2[(size_t)(row0 + q * 4 + r) * HH + col] = f2bf(acc2[nt][r]);
    }
}

// ================= fused agg2 + tail: 16 rows x 16 threads (4 parts x 4 slices) =============

#define TSTRIDE 36   // 32 + 4 pad floats
#define ATR 16       // rows per block

__global__ void k_aggtail(const ushort_t* __restrict__ y2, const int* __restrict__ deg,
                          const ushort_t* __restrict__ ell, const float* __restrict__ eps_p,
                          const float* __restrict__ b2a, const float* __restrict__ W2b,
                          const float* __restrict__ b2b, const float* __restrict__ Wh,
                          const float* __restrict__ bhp, float* __restrict__ out) {
    __shared__ float t2f[ATR * TSTRIDE];
    int row = threadIdx.x >> 4;        // 0..15
    int sub = threadIdx.x & 15;
    int jg = sub & 3;                  // 16B slice
    int part = sub >> 2;               // edge partition
    int i = blockIdx.x * ATR + row;
    bool live = i < NN;

    if (live) {
        const uint4* y4 = (const uint4*)y2;
        const ushort_t* er = ell + (size_t)i * ELLW;
        int d = min(deg[i], ELLW);
        float a0[8] = {0,0,0,0,0,0,0,0}, a1[8] = {0,0,0,0,0,0,0,0};
        int p = part;
        for (; p + 4 < d; p += 8) {
            int s0 = er[p], s1 = er[p + 4];
            uint4 f0 = y4[(size_t)s0 * 4 + jg];
            uint4 f1 = y4[(size_t)s1 * 4 + jg];
            addbf8(a0, f0); addbf8(a1, f1);
        }
        for (; p < d; p += 4) addbf8(a0, y4[(size_t)er[p] * 4 + jg]);

        float s[8];
#pragma unroll
        for (int k = 0; k < 8; ++k) {
            s[k] = a0[k] + a1[k];
            s[k] += __shfl_xor(s[k], 4);
            s[k] += __shfl_xor(s[k], 8);
        }
        if (part == 0) {
            uint4 su = y4[(size_t)i * 4 + jg];
            float s8[8];
            s8[0] = __uint_as_float(su.x << 16); s8[1] = __uint_as_float(su.x & 0xffff0000u);
            s8[2] = __uint_as_float(su.y << 16); s8[3] = __uint_as_float(su.y & 0xffff0000u);
            s8[4] = __uint_as_float(su.z << 16); s8[5] = __uint_as_float(su.z & 0xffff0000u);
            s8[6] = __uint_as_float(su.w << 16); s8[7] = __uint_as_float(su.w & 0xffff0000u);
            float4 bl = ((const float4*)b2a)[2 * jg];
            float4 bhv = ((const float4*)b2a)[2 * jg + 1];
            float bb[8] = {bl.x, bl.y, bl.z, bl.w, bhv.x, bhv.y, bhv.z, bhv.w};
            float e = 1.0f + eps_p[0];
#pragma unroll
            for (int k = 0; k < 8; ++k) {
                float vv = fmaf(e, s8[k], s[k]) + bb[k];
                t2f[row * TSTRIDE + jg * 8 + k] = fmaxf(vv, 0.0f);
            }
        }
    }
    __syncthreads();

    float o[OO] = {0.f, 0.f, 0.f, 0.f};
    if (live) {
        const float* tr = &t2f[row * TSTRIDE];
#pragma unroll
        for (int jj = 0; jj < 2; ++jj) {
            int j = sub * 2 + jj;
            float acc = b2b[j];
#pragma unroll 8
            for (int k = 0; k < HH; ++k)
                acc = fmaf(tr[k], W2b[k * HH + j], acc);
            acc = fmaxf(acc, 0.0f);
#pragma unroll
            for (int oo = 0; oo < OO; ++oo)
                o[oo] = fmaf(acc, Wh[j * OO + oo], o[oo]);
        }
    }
#pragma unroll
    for (int oo = 0; oo < OO; ++oo) {
        o[oo] += __shfl_xor(o[oo], 1);
        o[oo] += __shfl_xor(o[oo], 2);
        o[oo] += __shfl_xor(o[oo], 4);
        o[oo] += __shfl_xor(o[oo], 8);
    }
    if (live && sub == 0) {
        float4 ov = {o[0] + bhp[0], o[1] + bhp[1], o[2] + bhp[2], o[3] + bhp[3]};
        ((float4*)out)[i] = ov;
    }
}

// ================= launch =================

extern "C" void kernel_launch(void* const* d_in, const int* in_sizes, int n_in,
                              void* d_out, int out_size, void* d_ws, size_t ws_size,
                              hipStream_t stream) {
    const float* x    = (const float*)d_in[0];
    const int*   edges= (const int*)d_in[1];
    const float* eps1 = (const float*)d_in[2];
    const float* eps2 = (const float*)d_in[3];
    const float* W1a  = (const float*)d_in[4];
    const float* b1a  = (const float*)d_in[5];
    const float* W1b  = (const float*)d_in[6];
    const float* b1b  = (const float*)d_in[7];
    const float* W2a  = (const float*)d_in[8];
    const float* b2a  = (const float*)d_in[9];
    const float* W2b  = (const float*)d_in[10];
    const float* b2b  = (const float*)d_in[11];
    const float* Wh   = (const float*)d_in[12];
    const float* bh   = (const float*)d_in[13];

    auto al = [](size_t n) { return (n + 255) / 256 * 256; };
    char* w = (char*)d_ws;
    int*      bcnt   = (int*)w;      w += al((size_t)NBUCK * 4);
    uint_t*   packed = (uint_t*)w;   w += al((size_t)NBUCK * BCAP * 4);
    int*      deg    = (int*)w;      w += al((size_t)NN * 4);
    ushort_t* ell    = (ushort_t*)w; w += al((size_t)NN * ELLW * 2);
    ushort_t* wf     = (ushort_t*)w; w += al((size_t)(9216 + 3072) * 2);
    ushort_t* y1     = (ushort_t*)w; w += al((size_t)NN * DD * 2);   // 3 slabs of [NN][32]
    ushort_t* t1     = (ushort_t*)w; w += al((size_t)NN * DD * 2);
    ushort_t* y2     = (ushort_t*)w; w += al((size_t)NN * HH * 2);

    const int B = 256;

    hipMemsetAsync(bcnt, 0, (size_t)NBUCK * 4, stream);
    k_pre<<<BA_B + WF_B, B, 0, stream>>>(edges, bcnt, packed, W1b, W2a, wf);
    k_main<<<NBUCK + MFMA1_B, B, 0, stream>>>(bcnt, packed, ell, deg, x, W1a, y1);
    k_aggb96<<<(NN * 24 + B - 1) / B, B, 0, stream>>>(y1, deg, ell, eps1, b1a, t1);
    k_mfma23<<<MFMA1_B, B, 0, stream>>>(t1, wf, b1b, y2);
    k_aggtail<<<(NN + ATR - 1) / ATR, B, 0, stream>>>(y2, deg, ell, eps2, b2a, W2b, b2b,
                                                      Wh, bh, (float*)d_out);
}